// Round 1
// baseline (466.251 us; speedup 1.0000x reference)
//
#include <hip/hip_runtime.h>
#include <math.h>

// Problem constants (fixed by reference setup_inputs)
constexpr int B = 4, L = 2048, S = 2048, H = 8, D = 64;
constexpr int U  = 40;   // sample_k = min(5*ceil(ln(2048)), 2048)
constexpr int NT = 40;   // n_top    = min(5*ceil(ln(2048)), 2048)
constexpr int NCH = 8;   // S split into 8 chunks for the selected-query attention
constexpr int CS = S / NCH;          // 256
constexpr float SCALE = 0.125f;      // 1/sqrt(64)

// ---------------------------------------------------------------- K1: M scores
// One thread per (b, l, h) [h fastest for locality: q rows for consecutive h are
// contiguous, and all h share the same sampled s indices per l].
__global__ void k_compute_M(const float* __restrict__ q, const float* __restrict__ k,
                            const int* __restrict__ idx, float* __restrict__ M) {
    int t = blockIdx.x * blockDim.x + threadIdx.x;
    if (t >= B * L * H) return;
    int h = t % H;
    int bl = t / H;
    int l = bl % L;
    int b = bl / L;

    const float4* qr = (const float4*)(q + ((size_t)(b * L + l) * H + h) * D);
    float4 qv[16];
#pragma unroll
    for (int i = 0; i < 16; i++) qv[i] = qr[i];

    float vmax = -INFINITY, vsum = 0.f;
    for (int u = 0; u < U; u++) {
        int s = idx[l * U + u];
        const float4* kr = (const float4*)(k + ((size_t)(b * S + s) * H + h) * D);
        float acc = 0.f;
#pragma unroll
        for (int i = 0; i < 16; i++) {
            float4 kv = kr[i];
            acc += qv[i].x * kv.x + qv[i].y * kv.y + qv[i].z * kv.z + qv[i].w * kv.w;
        }
        vmax = fmaxf(vmax, acc);
        vsum += acc;
    }
    M[(size_t)(b * H + h) * L + l] = vmax - vsum / (float)S;
}

// ---------------------------------------------------------------- K2: top-40
// One block per (b,h). Iterative argmax with jax.lax.top_k tie-break
// (larger value wins; equal value -> smaller index wins).
__global__ void k_topk(const float* __restrict__ M, int* __restrict__ topidx) {
    int bh = blockIdx.x;
    const float* m = M + (size_t)bh * L;
    __shared__ float sv[L];        // 8 KB
    __shared__ float best_v[256];
    __shared__ int   best_i[256];
    int tid = threadIdx.x;
    for (int i = tid; i < L; i += 256) sv[i] = m[i];
    __syncthreads();
    for (int it = 0; it < NT; it++) {
        float bv = -INFINITY; int bi = 0x7fffffff;
        for (int i = tid; i < L; i += 256) {
            float v = sv[i];
            if (v > bv || (v == bv && i < bi)) { bv = v; bi = i; }
        }
        best_v[tid] = bv; best_i[tid] = bi;
        __syncthreads();
        for (int s2 = 128; s2 > 0; s2 >>= 1) {
            if (tid < s2) {
                float ov = best_v[tid + s2]; int oi = best_i[tid + s2];
                if (ov > best_v[tid] || (ov == best_v[tid] && oi < best_i[tid])) {
                    best_v[tid] = ov; best_i[tid] = oi;
                }
            }
            __syncthreads();
        }
        if (tid == 0) {
            topidx[bh * NT + it] = best_i[0];
            sv[best_i[0]] = -INFINITY;
        }
        __syncthreads();
    }
}

// ---------------------------------------------------------------- K3: v mean
__global__ void k_meanv(const float* __restrict__ v, float* __restrict__ meanv) {
    int bh = blockIdx.x; int b = bh / H, h = bh % H;
    int tid = threadIdx.x; int d = tid & 63; int g = tid >> 6; // 4 groups
    float acc = 0.f;
    for (int s = g; s < S; s += 4)
        acc += v[((size_t)(b * S + s) * H + h) * D + d];
    __shared__ float red[4][64];
    red[g][d] = acc;
    __syncthreads();
    if (g == 0)
        meanv[bh * D + d] = (red[0][d] + red[1][d] + red[2][d] + red[3][d]) / (float)S;
}

// ---------------------------------------------------------------- K4: attention partials
// One block per (bh, s-chunk). Produces per-chunk m, l, partial ctx.
__global__ void k_attn_part(const float* __restrict__ q, const float* __restrict__ k,
                            const float* __restrict__ v, const int* __restrict__ topidx,
                            float* __restrict__ pctx, float* __restrict__ pm,
                            float* __restrict__ pl) {
    int blk = blockIdx.x;
    int bh = blk / NCH, c = blk % NCH;
    int b = bh / H, h = bh % H;
    int s0 = c * CS;
    int tid = threadIdx.x;

    __shared__ float q_s[NT][D];          // 10 KB
    __shared__ float p_s[NT][CS + 1];     // padded: kills 40-lane bank conflict on row scans
    __shared__ float m_c[NT];

    for (int i = tid; i < NT * D; i += 256) {
        int n = i / D, d = i % D;
        int lsel = topidx[bh * NT + n];
        q_s[n][d] = q[((size_t)(b * L + lsel) * H + h) * D + d];
    }
    __syncthreads();

    // scores for s = s0 + tid
    int s = s0 + tid;
    const float4* kr = (const float4*)(k + ((size_t)(b * S + s) * H + h) * D);
    float4 kv[16];
#pragma unroll
    for (int i = 0; i < 16; i++) kv[i] = kr[i];

    float sc[NT];
#pragma unroll
    for (int n = 0; n < NT; n++) {
        const float4* qr = (const float4*)q_s[n];
        float acc = 0.f;
#pragma unroll
        for (int i = 0; i < 16; i++) {
            float4 qv = qr[i];
            acc += qv.x * kv[i].x + qv.y * kv[i].y + qv.z * kv[i].z + qv.w * kv[i].w;
        }
        sc[n] = acc * SCALE;
        p_s[n][tid] = sc[n];
    }
    __syncthreads();

    // per-n chunk max
    if (tid < NT) {
        float mx = -INFINITY;
        for (int j = 0; j < CS; j++) mx = fmaxf(mx, p_s[tid][j]);
        m_c[tid] = mx;
    }
    __syncthreads();

    // exponentiate
#pragma unroll
    for (int n = 0; n < NT; n++) p_s[n][tid] = __expf(sc[n] - m_c[n]);
    __syncthreads();

    // per-n chunk exp-sum
    if (tid < NT) {
        float sum = 0.f;
        for (int j = 0; j < CS; j++) sum += p_s[tid][j];
        pm[(bh * NCH + c) * NT + tid] = m_c[tid];
        pl[(bh * NCH + c) * NT + tid] = sum;
    }

    // partial ctx: group g handles n in [g*10, g*10+10), lane d = tid&63
    int d = tid & 63, g = tid >> 6;
    float acc[10];
#pragma unroll
    for (int j = 0; j < 10; j++) acc[j] = 0.f;
    for (int tt = 0; tt < CS; tt++) {
        float vd = v[((size_t)(b * S + s0 + tt) * H + h) * D + d];
#pragma unroll
        for (int j = 0; j < 10; j++) acc[j] += p_s[g * 10 + j][tt] * vd;
    }
    for (int j = 0; j < 10; j++)
        pctx[((size_t)(bh * NCH + c) * NT + g * 10 + j) * D + d] = acc[j];
}

// ---------------------------------------------------------------- K5: fill with mean
__global__ void k_fill(const float* __restrict__ meanv, float* __restrict__ out) {
    int i = blockIdx.x * blockDim.x + threadIdx.x; // over B*L*H*D = 2^22
    int d = i & 63;
    int h = (i >> 6) & 7;
    int b = i >> 20;
    out[i] = meanv[(b * H + h) * D + d];
}

// ---------------------------------------------------------------- K6: combine + scatter
__global__ void k_combine(const int* __restrict__ topidx, const float* __restrict__ pctx,
                          const float* __restrict__ pm, const float* __restrict__ pl,
                          float* __restrict__ out) {
    int bh = blockIdx.x; int b = bh / H, h = bh % H;
    int tid = threadIdx.x;
    for (int i = tid; i < NT * D; i += 256) {
        int n = i / D, d = i % D;
        float mg = -INFINITY;
#pragma unroll
        for (int c = 0; c < NCH; c++) mg = fmaxf(mg, pm[(bh * NCH + c) * NT + n]);
        float lsum = 0.f, ctx = 0.f;
#pragma unroll
        for (int c = 0; c < NCH; c++) {
            float w = __expf(pm[(bh * NCH + c) * NT + n] - mg);
            lsum += pl[(bh * NCH + c) * NT + n] * w;
            ctx  += pctx[((size_t)(bh * NCH + c) * NT + n) * D + d] * w;
        }
        int lsel = topidx[bh * NT + n];
        out[((size_t)(b * L + lsel) * H + h) * D + d] = ctx / lsum;
    }
}

// ---------------------------------------------------------------- launch
extern "C" void kernel_launch(void* const* d_in, const int* in_sizes, int n_in,
                              void* d_out, int out_size, void* d_ws, size_t ws_size,
                              hipStream_t stream) {
    const float* q   = (const float*)d_in[0];
    const float* k   = (const float*)d_in[1];
    const float* v   = (const float*)d_in[2];
    const int*   idx = (const int*)d_in[3];
    float* out = (float*)d_out;

    // workspace layout (floats)
    float* ws = (float*)d_ws;
    float* M      = ws;                         // B*H*L        = 65536
    int*   topidx = (int*)(ws + 65536);         // B*H*NT       = 1280 ints
    float* meanv  = ws + 65536 + 1280;          // B*H*D        = 2048
    float* pm     = meanv + 2048;               // B*H*NCH*NT   = 10240
    float* pl     = pm + 10240;                 // 10240
    float* pctx   = pl + 10240;                 // B*H*NCH*NT*D = 655360

    k_compute_M<<<(B * L * H) / 256, 256, 0, stream>>>(q, k, idx, M);
    k_topk<<<B * H, 256, 0, stream>>>(M, topidx);
    k_meanv<<<B * H, 256, 0, stream>>>(v, meanv);
    k_attn_part<<<B * H * NCH, 256, 0, stream>>>(q, k, v, topidx, pctx, pm, pl);
    k_fill<<<(B * L * H * D) / 256, 256, 0, stream>>>(meanv, out);
    k_combine<<<B * H, 256, 0, stream>>>(topidx, pctx, pm, pl, out);
}

// Round 2
// 337.258 us; speedup vs baseline: 1.3825x; 1.3825x over previous
//
#include <hip/hip_runtime.h>
#include <math.h>

constexpr int B = 4, L = 2048, S = 2048, H = 8, D = 64;
constexpr int U  = 40;
constexpr int NT = 40;
constexpr int NCH = 8;
constexpr int CS = S / NCH;          // 256
constexpr float SCALE = 0.125f;

// ---------------------------------------------------------------- K1: M scores
// One thread per (b, l, h), h fastest. Block=64 -> 512 blocks (fills 256 CUs).
__global__ void k_compute_M(const float* __restrict__ q, const float* __restrict__ k,
                            const int* __restrict__ idx, float* __restrict__ M) {
    int t = blockIdx.x * blockDim.x + threadIdx.x;
    int h = t % H;
    int bl = t / H;
    int l = bl % L;
    int b = bl / L;

    const float4* qr = (const float4*)(q + ((size_t)(b * L + l) * H + h) * D);
    float4 qv[16];
#pragma unroll
    for (int i = 0; i < 16; i++) qv[i] = qr[i];

    float vmax = -INFINITY, vsum = 0.f;
    for (int u = 0; u < U; u++) {
        int s = idx[l * U + u];
        const float4* kr = (const float4*)(k + ((size_t)(b * S + s) * H + h) * D);
        float acc = 0.f;
#pragma unroll
        for (int i = 0; i < 16; i++) {
            float4 kv = kr[i];
            acc += qv[i].x * kv.x + qv[i].y * kv.y + qv[i].z * kv.z + qv[i].w * kv.w;
        }
        vmax = fmaxf(vmax, acc);
        vsum += acc;
    }
    M[(size_t)(b * H + h) * L + l] = vmax - vsum / (float)S;
}

// ---------------------------------------------------------------- K2: top-40
// One block per (b,h). Wave-shuffle argmax, 2 barriers/iter instead of 9.
__global__ void k_topk(const float* __restrict__ M, int* __restrict__ topidx) {
    int bh = blockIdx.x;
    const float* m = M + (size_t)bh * L;
    __shared__ float sv[L];
    __shared__ float wv[4];
    __shared__ int   wi[4];
    int tid = threadIdx.x;
    int lane = tid & 63, wid = tid >> 6;
    for (int i = tid; i < L; i += 256) sv[i] = m[i];
    __syncthreads();
    for (int it = 0; it < NT; it++) {
        float bv = -INFINITY; int bi = 0x7fffffff;
        for (int i = tid; i < L; i += 256) {
            float x = sv[i];
            if (x > bv || (x == bv && i < bi)) { bv = x; bi = i; }
        }
#pragma unroll
        for (int off = 32; off > 0; off >>= 1) {
            float ov = __shfl_down(bv, off);
            int   oi = __shfl_down(bi, off);
            if (ov > bv || (ov == bv && oi < bi)) { bv = ov; bi = oi; }
        }
        if (lane == 0) { wv[wid] = bv; wi[wid] = bi; }
        __syncthreads();
        if (tid == 0) {
#pragma unroll
            for (int w = 1; w < 4; w++)
                if (wv[w] > bv || (wv[w] == bv && wi[w] < bi)) { bv = wv[w]; bi = wi[w]; }
            topidx[bh * NT + it] = bi;
            sv[bi] = -INFINITY;
        }
        __syncthreads();
    }
}

// ---------------------------------------------------------------- K3: v mean (2-phase)
// part aliases M's workspace (dead after k_topk). 128 blocks x 512 thr, coalesced.
__global__ void k_meanv_part(const float* __restrict__ v, float* __restrict__ part) {
    int blk = blockIdx.x;            // b*32 + c
    int b = blk >> 5, c = blk & 31;  // 32 chunks of 64 rows
    int col = threadIdx.x;           // 0..511 over H*D
    const float* p = v + ((size_t)(b * S + c * 64)) * 512 + col;
    float acc = 0.f;
#pragma unroll
    for (int s = 0; s < 64; s++) acc += p[(size_t)s * 512];
    part[(size_t)blk * 512 + col] = acc;
}

__global__ void k_meanv_final(const float* __restrict__ part, float* __restrict__ meanv) {
    int b = blockIdx.x; int col = threadIdx.x;
    float acc = 0.f;
#pragma unroll
    for (int c = 0; c < 32; c++) acc += part[(size_t)(b * 32 + c) * 512 + col];
    meanv[b * 512 + col] = acc * (1.f / (float)S);
}

// ---------------------------------------------------------------- K4: attention partials
__global__ void k_attn_part(const float* __restrict__ q, const float* __restrict__ k,
                            const float* __restrict__ v, const int* __restrict__ topidx,
                            float* __restrict__ pctx, float* __restrict__ pm,
                            float* __restrict__ pl) {
    int blk = blockIdx.x;
    int bh = blk / NCH, c = blk % NCH;
    int b = bh / H, h = bh % H;
    int s0 = c * CS;
    int tid = threadIdx.x;

    __shared__ float q_s[NT][D];           // 10 KB
    __shared__ float p_s[NT][CS + 4];      // stride 260 floats = 1040 B (16B-aligned rows)
    __shared__ float m_c[NT];

    for (int i = tid; i < NT * D; i += 256) {
        int n = i / D, d = i % D;
        int lsel = topidx[bh * NT + n];
        q_s[n][d] = q[((size_t)(b * L + lsel) * H + h) * D + d];
    }
    __syncthreads();

    int s = s0 + tid;
    const float4* kr = (const float4*)(k + ((size_t)(b * S + s) * H + h) * D);
    float4 kv[16];
#pragma unroll
    for (int i = 0; i < 16; i++) kv[i] = kr[i];

    float sc[NT];
#pragma unroll
    for (int n = 0; n < NT; n++) {
        const float4* qr = (const float4*)q_s[n];
        float acc = 0.f;
#pragma unroll
        for (int i = 0; i < 16; i++) {
            float4 qv = qr[i];
            acc += qv.x * kv[i].x + qv.y * kv[i].y + qv.z * kv[i].z + qv.w * kv[i].w;
        }
        sc[n] = acc * SCALE;
        p_s[n][tid] = sc[n];
    }
    __syncthreads();

    if (tid < NT) {
        float mx = -INFINITY;
        for (int j = 0; j < CS; j++) mx = fmaxf(mx, p_s[tid][j]);
        m_c[tid] = mx;
    }
    __syncthreads();

#pragma unroll
    for (int n = 0; n < NT; n++) p_s[n][tid] = __expf(sc[n] - m_c[n]);
    __syncthreads();

    if (tid < NT) {
        float sum = 0.f;
        for (int j = 0; j < CS; j++) sum += p_s[tid][j];
        pm[(bh * NCH + c) * NT + tid] = m_c[tid];
        pl[(bh * NCH + c) * NT + tid] = sum;
    }

    // partial ctx: wave g handles rows n in [g*10, g*10+10); lane d = tid&63
    int d = tid & 63, g = tid >> 6;
    float acc[10];
#pragma unroll
    for (int j = 0; j < 10; j++) acc[j] = 0.f;
    const float* vb = v + ((size_t)(b * S + s0) * H + h) * D + d;
    for (int t4 = 0; t4 < CS; t4 += 4) {
        float vd0 = vb[(size_t)(t4 + 0) * H * D];
        float vd1 = vb[(size_t)(t4 + 1) * H * D];
        float vd2 = vb[(size_t)(t4 + 2) * H * D];
        float vd3 = vb[(size_t)(t4 + 3) * H * D];
#pragma unroll
        for (int j = 0; j < 10; j++) {
            float4 p4 = *(const float4*)&p_s[g * 10 + j][t4];
            acc[j] += p4.x * vd0 + p4.y * vd1 + p4.z * vd2 + p4.w * vd3;
        }
    }
    for (int j = 0; j < 10; j++)
        pctx[((size_t)(bh * NCH + c) * NT + g * 10 + j) * D + d] = acc[j];
}

// ---------------------------------------------------------------- K5: fill with mean (float4)
__global__ void k_fill(const float* __restrict__ meanv, float4* __restrict__ out) {
    int i = blockIdx.x * blockDim.x + threadIdx.x;  // over B*L*H*D/4 = 2^20
    int b = i >> 18;
    int col4 = i & 127;
    out[i] = ((const float4*)meanv)[(b << 7) | col4];
}

// ---------------------------------------------------------------- K6: combine + scatter
__global__ void k_combine(const int* __restrict__ topidx, const float* __restrict__ pctx,
                          const float* __restrict__ pm, const float* __restrict__ pl,
                          float* __restrict__ out) {
    int bh = blockIdx.x; int b = bh / H, h = bh % H;
    int tid = threadIdx.x;
    for (int i = tid; i < NT * D; i += 256) {
        int n = i / D, d = i % D;
        float mg = -INFINITY;
#pragma unroll
        for (int c = 0; c < NCH; c++) mg = fmaxf(mg, pm[(bh * NCH + c) * NT + n]);
        float lsum = 0.f, ctx = 0.f;
#pragma unroll
        for (int c = 0; c < NCH; c++) {
            float w = __expf(pm[(bh * NCH + c) * NT + n] - mg);
            lsum += pl[(bh * NCH + c) * NT + n] * w;
            ctx  += pctx[((size_t)(bh * NCH + c) * NT + n) * D + d] * w;
        }
        int lsel = topidx[bh * NT + n];
        out[((size_t)(b * L + lsel) * H + h) * D + d] = ctx / lsum;
    }
}

// ---------------------------------------------------------------- launch
extern "C" void kernel_launch(void* const* d_in, const int* in_sizes, int n_in,
                              void* d_out, int out_size, void* d_ws, size_t ws_size,
                              hipStream_t stream) {
    const float* q   = (const float*)d_in[0];
    const float* k   = (const float*)d_in[1];
    const float* v   = (const float*)d_in[2];
    const int*   idx = (const int*)d_in[3];
    float* out = (float*)d_out;

    float* ws = (float*)d_ws;
    float* M      = ws;                         // B*H*L = 65536 (reused as meanv partials)
    int*   topidx = (int*)(ws + 65536);         // 1280 ints
    float* meanv  = ws + 65536 + 1280;          // 2048
    float* pm     = meanv + 2048;               // 10240
    float* pl     = pm + 10240;                 // 10240
    float* pctx   = pl + 10240;                 // 655360

    k_compute_M<<<(B * L * H) / 64, 64, 0, stream>>>(q, k, idx, M);
    k_topk<<<B * H, 256, 0, stream>>>(M, topidx);
    k_meanv_part<<<B * 32, 512, 0, stream>>>(v, M);       // aliases M (dead after topk)
    k_meanv_final<<<B, 512, 0, stream>>>(M, meanv);
    k_attn_part<<<B * H * NCH, 256, 0, stream>>>(q, k, v, topidx, pctx, pm, pl);
    k_fill<<<(B * L * H * D / 4) / 256, 256, 0, stream>>>(meanv, (float4*)out);
    k_combine<<<B * H, 256, 0, stream>>>(topidx, pctx, pm, pl, out);
}

// Round 3
// 248.918 us; speedup vs baseline: 1.8731x; 1.3549x over previous
//
#include <hip/hip_runtime.h>
#include <math.h>

constexpr int B = 4, L = 2048, S = 2048, H = 8, D = 64;
constexpr int U  = 40;
constexpr int NT = 40;
constexpr int NCH = 8;
constexpr int CS = S / NCH;          // 256
constexpr float SCALE = 0.125f;

// ---------------------------------------------------------------- K1: M scores
// One wave per (b,l). Lane = h*8+dg: wave reads full 2KB row k[b][s][:][:]
// coalesced; dot reduced over dg with 3 shuffles. b = blockIdx&3 -> each XCD
// (round-robin by blockIdx%8) touches exactly one batch's keys (4MB = L2 size).
__global__ void k_compute_M(const float* __restrict__ q, const float* __restrict__ k,
                            const int* __restrict__ idx, float* __restrict__ M) {
    int tid = threadIdx.x;
    int wid = tid >> 6, lane = tid & 63;
    int b = blockIdx.x & 3;
    int l = (blockIdx.x >> 2) * 4 + wid;
    int h = lane >> 3, dg = lane & 7;

    const float4* qr = (const float4*)(q + ((size_t)(b * L + l) * H + h) * D + dg * 8);
    float4 q0 = qr[0], q1 = qr[1];

    const int* irow = idx + l * U;
    const float* kb = k + (size_t)b * S * H * D + (size_t)h * D + dg * 8;
    float vmax = -INFINITY, vsum = 0.f;
#pragma unroll 4
    for (int u = 0; u < U; u++) {
        int s = irow[u];
        const float4* kr = (const float4*)(kb + (size_t)s * H * D);
        float4 k0 = kr[0], k1 = kr[1];
        float acc = q0.x * k0.x + q0.y * k0.y + q0.z * k0.z + q0.w * k0.w
                  + q1.x * k1.x + q1.y * k1.y + q1.z * k1.z + q1.w * k1.w;
        acc += __shfl_xor(acc, 1);
        acc += __shfl_xor(acc, 2);
        acc += __shfl_xor(acc, 4);
        vmax = fmaxf(vmax, acc);
        vsum += acc;
    }
    if (dg == 0) M[(size_t)(b * H + h) * L + l] = vmax - vsum / (float)S;
}

// ---------------------------------------------------------------- K2: top-40
__global__ void k_topk(const float* __restrict__ M, int* __restrict__ topidx) {
    int bh = blockIdx.x;
    const float* m = M + (size_t)bh * L;
    __shared__ float sv[L];
    __shared__ float wv[4];
    __shared__ int   wi[4];
    int tid = threadIdx.x;
    int lane = tid & 63, wid = tid >> 6;
    for (int i = tid; i < L; i += 256) sv[i] = m[i];
    __syncthreads();
    for (int it = 0; it < NT; it++) {
        float bv = -INFINITY; int bi = 0x7fffffff;
        for (int i = tid; i < L; i += 256) {
            float x = sv[i];
            if (x > bv || (x == bv && i < bi)) { bv = x; bi = i; }
        }
#pragma unroll
        for (int off = 32; off > 0; off >>= 1) {
            float ov = __shfl_down(bv, off);
            int   oi = __shfl_down(bi, off);
            if (ov > bv || (ov == bv && oi < bi)) { bv = ov; bi = oi; }
        }
        if (lane == 0) { wv[wid] = bv; wi[wid] = bi; }
        __syncthreads();
        if (tid == 0) {
#pragma unroll
            for (int w = 1; w < 4; w++)
                if (wv[w] > bv || (wv[w] == bv && wi[w] < bi)) { bv = wv[w]; bi = wi[w]; }
            topidx[bh * NT + it] = bi;
            sv[bi] = -INFINITY;
        }
        __syncthreads();
    }
}

// ---------------------------------------------------------------- K3: v mean (2-phase)
__global__ void k_meanv_part(const float* __restrict__ v, float* __restrict__ part) {
    int blk = blockIdx.x;            // b*32 + c
    int b = blk >> 5, c = blk & 31;
    int col = threadIdx.x;           // 0..511 over H*D
    const float* p = v + ((size_t)(b * S + c * 64)) * 512 + col;
    float acc = 0.f;
#pragma unroll
    for (int s = 0; s < 64; s++) acc += p[(size_t)s * 512];
    part[(size_t)blk * 512 + col] = acc;
}

__global__ void k_meanv_final(const float* __restrict__ part, float* __restrict__ meanv) {
    int b = blockIdx.x; int col = threadIdx.x;
    float acc = 0.f;
#pragma unroll
    for (int c = 0; c < 32; c++) acc += part[(size_t)(b * 32 + c) * 512 + col];
    meanv[b * 512 + col] = acc * (1.f / (float)S);
}

// ---------------------------------------------------------------- K4: attention partials
__global__ void k_attn_part(const float* __restrict__ q, const float* __restrict__ k,
                            const float* __restrict__ v, const int* __restrict__ topidx,
                            float* __restrict__ pctx, float* __restrict__ pm,
                            float* __restrict__ pl) {
    int blk = blockIdx.x;
    int bh = blk / NCH, c = blk % NCH;
    int b = bh / H, h = bh % H;
    int s0 = c * CS;
    int tid = threadIdx.x;

    __shared__ float q_s[NT][D];
    __shared__ float p_s[NT][CS + 4];
    __shared__ float m_c[NT];

    for (int i = tid; i < NT * D; i += 256) {
        int n = i / D, d = i % D;
        int lsel = topidx[bh * NT + n];
        q_s[n][d] = q[((size_t)(b * L + lsel) * H + h) * D + d];
    }
    __syncthreads();

    int s = s0 + tid;
    const float4* kr = (const float4*)(k + ((size_t)(b * S + s) * H + h) * D);
    float4 kv[16];
#pragma unroll
    for (int i = 0; i < 16; i++) kv[i] = kr[i];

    float sc[NT];
#pragma unroll
    for (int n = 0; n < NT; n++) {
        const float4* qr = (const float4*)q_s[n];
        float acc = 0.f;
#pragma unroll
        for (int i = 0; i < 16; i++) {
            float4 qv = qr[i];
            acc += qv.x * kv[i].x + qv.y * kv[i].y + qv.z * kv[i].z + qv.w * kv[i].w;
        }
        sc[n] = acc * SCALE;
        p_s[n][tid] = sc[n];
    }
    __syncthreads();

    if (tid < NT) {
        float mx = -INFINITY;
        for (int j = 0; j < CS; j++) mx = fmaxf(mx, p_s[tid][j]);
        m_c[tid] = mx;
    }
    __syncthreads();

#pragma unroll
    for (int n = 0; n < NT; n++) p_s[n][tid] = __expf(sc[n] - m_c[n]);
    __syncthreads();

    if (tid < NT) {
        float sum = 0.f;
        for (int j = 0; j < CS; j++) sum += p_s[tid][j];
        pm[(bh * NCH + c) * NT + tid] = m_c[tid];
        pl[(bh * NCH + c) * NT + tid] = sum;
    }

    int d = tid & 63, g = tid >> 6;
    float acc[10];
#pragma unroll
    for (int j = 0; j < 10; j++) acc[j] = 0.f;
    const float* vb = v + ((size_t)(b * S + s0) * H + h) * D + d;
    for (int t4 = 0; t4 < CS; t4 += 4) {
        float vd0 = vb[(size_t)(t4 + 0) * H * D];
        float vd1 = vb[(size_t)(t4 + 1) * H * D];
        float vd2 = vb[(size_t)(t4 + 2) * H * D];
        float vd3 = vb[(size_t)(t4 + 3) * H * D];
#pragma unroll
        for (int j = 0; j < 10; j++) {
            float4 p4 = *(const float4*)&p_s[g * 10 + j][t4];
            acc[j] += p4.x * vd0 + p4.y * vd1 + p4.z * vd2 + p4.w * vd3;
        }
    }
    for (int j = 0; j < 10; j++)
        pctx[((size_t)(bh * NCH + c) * NT + g * 10 + j) * D + d] = acc[j];
}

// ---------------------------------------------------------------- K5: fill with mean
__global__ void k_fill(const float* __restrict__ meanv, float4* __restrict__ out) {
    int i = blockIdx.x * blockDim.x + threadIdx.x;
    int b = i >> 18;
    int col4 = i & 127;
    out[i] = ((const float4*)meanv)[(b << 7) | col4];
}

// ---------------------------------------------------------------- K6: combine + scatter
__global__ void k_combine(const int* __restrict__ topidx, const float* __restrict__ pctx,
                          const float* __restrict__ pm, const float* __restrict__ pl,
                          float* __restrict__ out) {
    int bh = blockIdx.x; int b = bh / H, h = bh % H;
    int tid = threadIdx.x;
    for (int i = tid; i < NT * D; i += 256) {
        int n = i / D, d = i % D;
        float mg = -INFINITY;
#pragma unroll
        for (int c = 0; c < NCH; c++) mg = fmaxf(mg, pm[(bh * NCH + c) * NT + n]);
        float lsum = 0.f, ctx = 0.f;
#pragma unroll
        for (int c = 0; c < NCH; c++) {
            float w = __expf(pm[(bh * NCH + c) * NT + n] - mg);
            lsum += pl[(bh * NCH + c) * NT + n] * w;
            ctx  += pctx[((size_t)(bh * NCH + c) * NT + n) * D + d] * w;
        }
        int lsel = topidx[bh * NT + n];
        out[((size_t)(b * L + lsel) * H + h) * D + d] = ctx / lsum;
    }
}

// ---------------------------------------------------------------- launch
extern "C" void kernel_launch(void* const* d_in, const int* in_sizes, int n_in,
                              void* d_out, int out_size, void* d_ws, size_t ws_size,
                              hipStream_t stream) {
    const float* q   = (const float*)d_in[0];
    const float* k   = (const float*)d_in[1];
    const float* v   = (const float*)d_in[2];
    const int*   idx = (const int*)d_in[3];
    float* out = (float*)d_out;

    float* ws = (float*)d_ws;
    float* M      = ws;                         // B*H*L = 65536 (reused as meanv partials)
    int*   topidx = (int*)(ws + 65536);         // 1280 ints
    float* meanv  = ws + 65536 + 1280;          // 2048
    float* pm     = meanv + 2048;               // 10240
    float* pl     = pm + 10240;                 // 10240
    float* pctx   = pl + 10240;                 // 655360

    k_compute_M<<<B * L / 4, 256, 0, stream>>>(q, k, idx, M);
    k_topk<<<B * H, 256, 0, stream>>>(M, topidx);
    k_meanv_part<<<B * 32, 512, 0, stream>>>(v, M);
    k_meanv_final<<<B, 512, 0, stream>>>(M, meanv);
    k_attn_part<<<B * H * NCH, 256, 0, stream>>>(q, k, v, topidx, pctx, pm, pl);
    k_fill<<<(B * L * H * D / 4) / 256, 256, 0, stream>>>(meanv, (float4*)out);
    k_combine<<<B * H, 256, 0, stream>>>(topidx, pctx, pm, pl, out);
}

// Round 4
// 236.611 us; speedup vs baseline: 1.9705x; 1.0520x over previous
//
#include <hip/hip_runtime.h>
#include <math.h>

constexpr int B = 4, L = 2048, S = 2048, H = 8, D = 64;
constexpr int U  = 40;
constexpr int NT = 40;
constexpr int NCH = 8;
constexpr int CS = S / NCH;          // 256
constexpr float SCALE = 0.125f;

// ---------------------------------------------------------------- K1: M scores
// One wave per (b,l). Lane = h*8+dg: wave reads full 2KB row k[b][s][:][:]
// coalesced; dot reduced over dg with 3 shuffles. b = blockIdx&3 -> each XCD
// (round-robin by blockIdx%8) touches mostly one batch's keys.
__global__ void k_compute_M(const float* __restrict__ q, const float* __restrict__ k,
                            const int* __restrict__ idx, float* __restrict__ M) {
    int tid = threadIdx.x;
    int wid = tid >> 6, lane = tid & 63;
    int b = blockIdx.x & 3;
    int l = (blockIdx.x >> 2) * 4 + wid;
    int h = lane >> 3, dg = lane & 7;

    const float4* qr = (const float4*)(q + ((size_t)(b * L + l) * H + h) * D + dg * 8);
    float4 q0 = qr[0], q1 = qr[1];

    const int* irow = idx + l * U;
    const float* kb = k + (size_t)b * S * H * D + (size_t)h * D + dg * 8;
    float vmax = -INFINITY, vsum = 0.f;
#pragma unroll 4
    for (int u = 0; u < U; u++) {
        int s = irow[u];
        const float4* kr = (const float4*)(kb + (size_t)s * H * D);
        float4 k0 = kr[0], k1 = kr[1];
        float acc = q0.x * k0.x + q0.y * k0.y + q0.z * k0.z + q0.w * k0.w
                  + q1.x * k1.x + q1.y * k1.y + q1.z * k1.z + q1.w * k1.w;
        acc += __shfl_xor(acc, 1);
        acc += __shfl_xor(acc, 2);
        acc += __shfl_xor(acc, 4);
        vmax = fmaxf(vmax, acc);
        vsum += acc;
    }
    if (dg == 0) M[(size_t)(b * H + h) * L + l] = vmax - vsum / (float)S;
}

// ---------------------------------------------------------------- K2: top-40
// One block per (b,h), 8 waves. Wave w holds chunk [w*256, w*256+256) in regs
// (4 vals/lane) and extracts its top-40 via shuffle-butterfly argmax with
// in-register invalidation — no barriers/LDS in the loop. Wave 0 then merges
// the 8x40 candidates (5/lane). Tie-break everywhere: value desc, index asc.
__global__ void k_topk(const float* __restrict__ M, int* __restrict__ topidx) {
    int bh = blockIdx.x;
    const float* m = M + (size_t)bh * L;
    int tid = threadIdx.x;
    int lane = tid & 63, w = tid >> 6;
    __shared__ float cv[8][NT];
    __shared__ int   ci[8][NT];

    float x[4];
    int base = w * 256 + lane;
#pragma unroll
    for (int j = 0; j < 4; j++) x[j] = m[base + 64 * j];

    for (int it = 0; it < NT; it++) {
        float bv = x[0]; int bi = base;
#pragma unroll
        for (int j = 1; j < 4; j++)
            if (x[j] > bv) { bv = x[j]; bi = base + 64 * j; }  // idx asc: > only
#pragma unroll
        for (int off = 1; off < 64; off <<= 1) {
            float ov = __shfl_xor(bv, off);
            int   oi = __shfl_xor(bi, off);
            if (ov > bv || (ov == bv && oi < bi)) { bv = ov; bi = oi; }
        }
        // all lanes agree on (bv, bi): invalidate owner slot in-register
        int rel = bi - w * 256;
        if ((rel & 63) == lane) x[rel >> 6] = -INFINITY;
        if (lane == 0) { cv[w][it] = bv; ci[w][it] = bi; }
    }
    __syncthreads();

    if (w == 0) {
        float y[5]; int yi[5];
#pragma unroll
        for (int j = 0; j < 5; j++) {
            int c = lane + 64 * j;          // 0..319
            y[j]  = cv[c / NT][c % NT];
            yi[j] = ci[c / NT][c % NT];
        }
        for (int it = 0; it < NT; it++) {
            float bv = y[0]; int bi = yi[0];
#pragma unroll
            for (int j = 1; j < 5; j++)
                if (y[j] > bv || (y[j] == bv && yi[j] < bi)) { bv = y[j]; bi = yi[j]; }
#pragma unroll
            for (int off = 1; off < 64; off <<= 1) {
                float ov = __shfl_xor(bv, off);
                int   oi = __shfl_xor(bi, off);
                if (ov > bv || (ov == bv && oi < bi)) { bv = ov; bi = oi; }
            }
#pragma unroll
            for (int j = 0; j < 5; j++)
                if (yi[j] == bi) y[j] = -INFINITY;   // l-indices unique -> safe
            if (lane == 0) topidx[bh * NT + it] = bi;
        }
    }
}

// ---------------------------------------------------------------- K3: v mean (2-phase)
__global__ void k_meanv_part(const float* __restrict__ v, float* __restrict__ part) {
    int blk = blockIdx.x;            // b*32 + c
    int b = blk >> 5, c = blk & 31;
    int col = threadIdx.x;           // 0..511 over H*D
    const float* p = v + ((size_t)(b * S + c * 64)) * 512 + col;
    float acc = 0.f;
#pragma unroll
    for (int s = 0; s < 64; s++) acc += p[(size_t)s * 512];
    part[(size_t)blk * 512 + col] = acc;
}

__global__ void k_meanv_final(const float* __restrict__ part, float* __restrict__ meanv) {
    int b = blockIdx.x; int col = threadIdx.x;
    float acc = 0.f;
#pragma unroll
    for (int c = 0; c < 32; c++) acc += part[(size_t)(b * 32 + c) * 512 + col];
    meanv[b * 512 + col] = acc * (1.f / (float)S);
}

// ---------------------------------------------------------------- K4: attention partials
__global__ void k_attn_part(const float* __restrict__ q, const float* __restrict__ k,
                            const float* __restrict__ v, const int* __restrict__ topidx,
                            float* __restrict__ pctx, float* __restrict__ pm,
                            float* __restrict__ pl) {
    int blk = blockIdx.x;
    int bh = blk / NCH, c = blk % NCH;
    int b = bh / H, h = bh % H;
    int s0 = c * CS;
    int tid = threadIdx.x;

    __shared__ float q_s[NT][D];
    __shared__ float p_s[NT][CS + 4];
    __shared__ float m_c[NT];

    for (int i = tid; i < NT * D; i += 256) {
        int n = i / D, d = i % D;
        int lsel = topidx[bh * NT + n];
        q_s[n][d] = q[((size_t)(b * L + lsel) * H + h) * D + d];
    }
    __syncthreads();

    int s = s0 + tid;
    const float4* kr = (const float4*)(k + ((size_t)(b * S + s) * H + h) * D);
    float4 kv[16];
#pragma unroll
    for (int i = 0; i < 16; i++) kv[i] = kr[i];

    float sc[NT];
#pragma unroll
    for (int n = 0; n < NT; n++) {
        const float4* qr = (const float4*)q_s[n];
        float acc = 0.f;
#pragma unroll
        for (int i = 0; i < 16; i++) {
            float4 qv = qr[i];
            acc += qv.x * kv[i].x + qv.y * kv[i].y + qv.z * kv[i].z + qv.w * kv[i].w;
        }
        sc[n] = acc * SCALE;
        p_s[n][tid] = sc[n];
    }
    __syncthreads();

    if (tid < NT) {
        float mx = -INFINITY;
        for (int j = 0; j < CS; j++) mx = fmaxf(mx, p_s[tid][j]);
        m_c[tid] = mx;
    }
    __syncthreads();

#pragma unroll
    for (int n = 0; n < NT; n++) p_s[n][tid] = __expf(sc[n] - m_c[n]);
    __syncthreads();

    if (tid < NT) {
        float sum = 0.f;
        for (int j = 0; j < CS; j++) sum += p_s[tid][j];
        pm[(bh * NCH + c) * NT + tid] = m_c[tid];
        pl[(bh * NCH + c) * NT + tid] = sum;
    }

    int d = tid & 63, g = tid >> 6;
    float acc[10];
#pragma unroll
    for (int j = 0; j < 10; j++) acc[j] = 0.f;
    const float* vb = v + ((size_t)(b * S + s0) * H + h) * D + d;
    for (int t4 = 0; t4 < CS; t4 += 4) {
        float vd0 = vb[(size_t)(t4 + 0) * H * D];
        float vd1 = vb[(size_t)(t4 + 1) * H * D];
        float vd2 = vb[(size_t)(t4 + 2) * H * D];
        float vd3 = vb[(size_t)(t4 + 3) * H * D];
#pragma unroll
        for (int j = 0; j < 10; j++) {
            float4 p4 = *(const float4*)&p_s[g * 10 + j][t4];
            acc[j] += p4.x * vd0 + p4.y * vd1 + p4.z * vd2 + p4.w * vd3;
        }
    }
    for (int j = 0; j < 10; j++)
        pctx[((size_t)(bh * NCH + c) * NT + g * 10 + j) * D + d] = acc[j];
}

// ---------------------------------------------------------------- K5: fill with mean
__global__ void k_fill(const float* __restrict__ meanv, float4* __restrict__ out) {
    int i = blockIdx.x * blockDim.x + threadIdx.x;
    int b = i >> 18;
    int col4 = i & 127;
    out[i] = ((const float4*)meanv)[(b << 7) | col4];
}

// ---------------------------------------------------------------- K6: combine + scatter
__global__ void k_combine(const int* __restrict__ topidx, const float* __restrict__ pctx,
                          const float* __restrict__ pm, const float* __restrict__ pl,
                          float* __restrict__ out) {
    int bh = blockIdx.x; int b = bh / H, h = bh % H;
    int tid = threadIdx.x;
    for (int i = tid; i < NT * D; i += 256) {
        int n = i / D, d = i % D;
        float mg = -INFINITY;
#pragma unroll
        for (int c = 0; c < NCH; c++) mg = fmaxf(mg, pm[(bh * NCH + c) * NT + n]);
        float lsum = 0.f, ctx = 0.f;
#pragma unroll
        for (int c = 0; c < NCH; c++) {
            float w = __expf(pm[(bh * NCH + c) * NT + n] - mg);
            lsum += pl[(bh * NCH + c) * NT + n] * w;
            ctx  += pctx[((size_t)(bh * NCH + c) * NT + n) * D + d] * w;
        }
        int lsel = topidx[bh * NT + n];
        out[((size_t)(b * L + lsel) * H + h) * D + d] = ctx / lsum;
    }
}

// ---------------------------------------------------------------- launch
extern "C" void kernel_launch(void* const* d_in, const int* in_sizes, int n_in,
                              void* d_out, int out_size, void* d_ws, size_t ws_size,
                              hipStream_t stream) {
    const float* q   = (const float*)d_in[0];
    const float* k   = (const float*)d_in[1];
    const float* v   = (const float*)d_in[2];
    const int*   idx = (const int*)d_in[3];
    float* out = (float*)d_out;

    float* ws = (float*)d_ws;
    float* M      = ws;                         // B*H*L = 65536 (reused as meanv partials)
    int*   topidx = (int*)(ws + 65536);         // 1280 ints
    float* meanv  = ws + 65536 + 1280;          // 2048
    float* pm     = meanv + 2048;               // 10240
    float* pl     = pm + 10240;                 // 10240
    float* pctx   = pl + 10240;                 // 655360

    k_compute_M<<<B * L / 4, 256, 0, stream>>>(q, k, idx, M);
    k_topk<<<B * H, 512, 0, stream>>>(M, topidx);
    k_meanv_part<<<B * 32, 512, 0, stream>>>(v, M);
    k_meanv_final<<<B, 512, 0, stream>>>(M, meanv);
    k_attn_part<<<B * H * NCH, 256, 0, stream>>>(q, k, v, topidx, pctx, pm, pl);
    k_fill<<<(B * L * H * D / 4) / 256, 256, 0, stream>>>(meanv, (float4*)out);
    k_combine<<<B * H, 256, 0, stream>>>(topidx, pctx, pm, pl, out);
}

// Round 5
// 215.518 us; speedup vs baseline: 2.1634x; 1.0979x over previous
//
#include <hip/hip_runtime.h>
#include <math.h>

constexpr int B = 4, L = 2048, S = 2048, H = 8, D = 64;
constexpr int U  = 40;
constexpr int NT = 40;
constexpr int NCH = 8;
constexpr int CS = S / NCH;          // 256
constexpr float SCALE = 0.125f;

// ---------------------------------------------------------------- K1: M scores
// One wave per (b,l). Lane = h*8+dg: wave reads full 2KB row k[b][s][:][:]
// coalesced; dot reduced over dg with 3 shuffles. b = blockIdx&3 -> XCD-local keys.
__global__ void k_compute_M(const float* __restrict__ q, const float* __restrict__ k,
                            const int* __restrict__ idx, float* __restrict__ M) {
    int tid = threadIdx.x;
    int wid = tid >> 6, lane = tid & 63;
    int b = blockIdx.x & 3;
    int l = (blockIdx.x >> 2) * 4 + wid;
    int h = lane >> 3, dg = lane & 7;

    const float4* qr = (const float4*)(q + ((size_t)(b * L + l) * H + h) * D + dg * 8);
    float4 q0 = qr[0], q1 = qr[1];

    const int* irow = idx + l * U;
    const float* kb = k + (size_t)b * S * H * D + (size_t)h * D + dg * 8;
    float vmax = -INFINITY, vsum = 0.f;
#pragma unroll 4
    for (int u = 0; u < U; u++) {
        int s = irow[u];
        const float4* kr = (const float4*)(kb + (size_t)s * H * D);
        float4 k0 = kr[0], k1 = kr[1];
        float acc = q0.x * k0.x + q0.y * k0.y + q0.z * k0.z + q0.w * k0.w
                  + q1.x * k1.x + q1.y * k1.y + q1.z * k1.z + q1.w * k1.w;
        acc += __shfl_xor(acc, 1);
        acc += __shfl_xor(acc, 2);
        acc += __shfl_xor(acc, 4);
        vmax = fmaxf(vmax, acc);
        vsum += acc;
    }
    if (dg == 0) M[(size_t)(b * H + h) * L + l] = vmax - vsum / (float)S;
}

// ---------------------------------------------------------------- K2: top-40 via radix select
// One block of 256 threads per (b,h). Keys as order-preserving uints, 8/thread
// in registers. 4 MSB-first byte levels: LDS histogram + thread-0 top-down scan
// -> exact 40th key T. Select o>T plus smallest-index ties. Output order
// arbitrary (only the index SET matters downstream).
__device__ inline unsigned int fkey(float f) {
    unsigned int u = __float_as_uint(f);
    return (u & 0x80000000u) ? ~u : (u | 0x80000000u);
}

__global__ void k_topk(const float* __restrict__ M, int* __restrict__ topidx) {
    int bh = blockIdx.x;
    const float* m = M + (size_t)bh * L;
    int tid = threadIdx.x;

    __shared__ int hist[256];
    __shared__ unsigned int prefix_s;
    __shared__ int c_above_s, nsel_s, ntie_s, r_s;
    __shared__ int tie_i[L];   // worst-case ties

    // load 8 elements/thread (two float4s), convert to ordered keys
    unsigned int o[8];
    const float4* mr = (const float4*)(m + tid * 8);
    float4 a0 = mr[0], a1 = mr[1];
    o[0] = fkey(a0.x); o[1] = fkey(a0.y); o[2] = fkey(a0.z); o[3] = fkey(a0.w);
    o[4] = fkey(a1.x); o[5] = fkey(a1.y); o[6] = fkey(a1.z); o[7] = fkey(a1.w);

    if (tid == 0) { prefix_s = 0u; c_above_s = 0; nsel_s = 0; ntie_s = 0; }

    // 4 byte-levels, MSB first
    for (int sh = 24; sh >= 0; sh -= 8) {
        hist[tid] = 0;
        __syncthreads();
        unsigned int pfx = prefix_s;
#pragma unroll
        for (int j = 0; j < 8; j++) {
            bool match = (sh == 24) || ((o[j] >> (sh + 8)) == (pfx >> (sh + 8)));
            if (match) atomicAdd(&hist[(o[j] >> sh) & 0xFF], 1);
        }
        __syncthreads();
        if (tid == 0) {
            int acc = c_above_s, bstar = 0;
            for (int j2 = 255; j2 >= 0; j2--) {
                int c = hist[j2];
                if (acc + c >= NT) { bstar = j2; break; }
                acc += c;
            }
            c_above_s = acc;
            prefix_s = prefix_s | ((unsigned int)bstar << sh);
        }
        __syncthreads();
    }

    unsigned int T = prefix_s;

    // phase 1: strictly-greater -> selected; equal -> tie list
#pragma unroll
    for (int j = 0; j < 8; j++) {
        if (o[j] > T) {
            int slot = atomicAdd(&nsel_s, 1);
            topidx[bh * NT + slot] = tid * 8 + j;
        } else if (o[j] == T) {
            int p = atomicAdd(&ntie_s, 1);
            tie_i[p] = tid * 8 + j;
        }
    }
    __syncthreads();
    if (tid == 0) r_s = NT - nsel_s;
    __syncthreads();
    int r = r_s, ntie = ntie_s;

    // phase 2: ties -> take r smallest indices (rank by scan; ntie tiny in practice)
#pragma unroll
    for (int j = 0; j < 8; j++) {
        if (o[j] == T) {
            int myidx = tid * 8 + j;
            int rank = 0;
            for (int p = 0; p < ntie; p++) rank += (tie_i[p] < myidx) ? 1 : 0;
            if (rank < r) {
                int slot = atomicAdd(&nsel_s, 1);
                topidx[bh * NT + slot] = myidx;
            }
        }
    }
}

// ---------------------------------------------------------------- K3: v mean (2-phase)
__global__ void k_meanv_part(const float* __restrict__ v, float* __restrict__ part) {
    int blk = blockIdx.x;            // b*32 + c
    int b = blk >> 5, c = blk & 31;
    int col = threadIdx.x;           // 0..511 over H*D
    const float* p = v + ((size_t)(b * S + c * 64)) * 512 + col;
    float acc = 0.f;
#pragma unroll
    for (int s = 0; s < 64; s++) acc += p[(size_t)s * 512];
    part[(size_t)blk * 512 + col] = acc;
}

__global__ void k_meanv_final(const float* __restrict__ part, float* __restrict__ meanv) {
    int b = blockIdx.x; int col = threadIdx.x;
    float acc = 0.f;
#pragma unroll
    for (int c = 0; c < 32; c++) acc += part[(size_t)(b * 32 + c) * 512 + col];
    meanv[b * 512 + col] = acc * (1.f / (float)S);
}

// ---------------------------------------------------------------- K4: attention partials
__global__ void k_attn_part(const float* __restrict__ q, const float* __restrict__ k,
                            const float* __restrict__ v, const int* __restrict__ topidx,
                            float* __restrict__ pctx, float* __restrict__ pm,
                            float* __restrict__ pl) {
    int blk = blockIdx.x;
    int bh = blk / NCH, c = blk % NCH;
    int b = bh / H, h = bh % H;
    int s0 = c * CS;
    int tid = threadIdx.x;

    __shared__ float q_s[NT][D];
    __shared__ float p_s[NT][CS + 4];
    __shared__ float m_c[NT];

    for (int i = tid; i < NT * D; i += 256) {
        int n = i / D, d = i % D;
        int lsel = topidx[bh * NT + n];
        q_s[n][d] = q[((size_t)(b * L + lsel) * H + h) * D + d];
    }
    __syncthreads();

    int s = s0 + tid;
    const float4* kr = (const float4*)(k + ((size_t)(b * S + s) * H + h) * D);
    float4 kv[16];
#pragma unroll
    for (int i = 0; i < 16; i++) kv[i] = kr[i];

    float sc[NT];
#pragma unroll
    for (int n = 0; n < NT; n++) {
        const float4* qr = (const float4*)q_s[n];
        float acc = 0.f;
#pragma unroll
        for (int i = 0; i < 16; i++) {
            float4 qv = qr[i];
            acc += qv.x * kv[i].x + qv.y * kv[i].y + qv.z * kv[i].z + qv.w * kv[i].w;
        }
        sc[n] = acc * SCALE;
        p_s[n][tid] = sc[n];
    }
    __syncthreads();

    if (tid < NT) {
        float mx = -INFINITY;
        for (int j = 0; j < CS; j++) mx = fmaxf(mx, p_s[tid][j]);
        m_c[tid] = mx;
    }
    __syncthreads();

#pragma unroll
    for (int n = 0; n < NT; n++) p_s[n][tid] = __expf(sc[n] - m_c[n]);
    __syncthreads();

    if (tid < NT) {
        float sum = 0.f;
        for (int j = 0; j < CS; j++) sum += p_s[tid][j];
        pm[(bh * NCH + c) * NT + tid] = m_c[tid];
        pl[(bh * NCH + c) * NT + tid] = sum;
    }

    int d = tid & 63, g = tid >> 6;
    float acc[10];
#pragma unroll
    for (int j = 0; j < 10; j++) acc[j] = 0.f;
    const float* vb = v + ((size_t)(b * S + s0) * H + h) * D + d;
    for (int t4 = 0; t4 < CS; t4 += 4) {
        float vd0 = vb[(size_t)(t4 + 0) * H * D];
        float vd1 = vb[(size_t)(t4 + 1) * H * D];
        float vd2 = vb[(size_t)(t4 + 2) * H * D];
        float vd3 = vb[(size_t)(t4 + 3) * H * D];
#pragma unroll
        for (int j = 0; j < 10; j++) {
            float4 p4 = *(const float4*)&p_s[g * 10 + j][t4];
            acc[j] += p4.x * vd0 + p4.y * vd1 + p4.z * vd2 + p4.w * vd3;
        }
    }
    for (int j = 0; j < 10; j++)
        pctx[((size_t)(bh * NCH + c) * NT + g * 10 + j) * D + d] = acc[j];
}

// ---------------------------------------------------------------- K5: fill with mean
__global__ void k_fill(const float* __restrict__ meanv, float4* __restrict__ out) {
    int i = blockIdx.x * blockDim.x + threadIdx.x;
    int b = i >> 18;
    int col4 = i & 127;
    out[i] = ((const float4*)meanv)[(b << 7) | col4];
}

// ---------------------------------------------------------------- K6: combine + scatter
__global__ void k_combine(const int* __restrict__ topidx, const float* __restrict__ pctx,
                          const float* __restrict__ pm, const float* __restrict__ pl,
                          float* __restrict__ out) {
    int bh = blockIdx.x; int b = bh / H, h = bh % H;
    int tid = threadIdx.x;
    for (int i = tid; i < NT * D; i += 256) {
        int n = i / D, d = i % D;
        float mg = -INFINITY;
#pragma unroll
        for (int c = 0; c < NCH; c++) mg = fmaxf(mg, pm[(bh * NCH + c) * NT + n]);
        float lsum = 0.f, ctx = 0.f;
#pragma unroll
        for (int c = 0; c < NCH; c++) {
            float w = __expf(pm[(bh * NCH + c) * NT + n] - mg);
            lsum += pl[(bh * NCH + c) * NT + n] * w;
            ctx  += pctx[((size_t)(bh * NCH + c) * NT + n) * D + d] * w;
        }
        int lsel = topidx[bh * NT + n];
        out[((size_t)(b * L + lsel) * H + h) * D + d] = ctx / lsum;
    }
}

// ---------------------------------------------------------------- launch
extern "C" void kernel_launch(void* const* d_in, const int* in_sizes, int n_in,
                              void* d_out, int out_size, void* d_ws, size_t ws_size,
                              hipStream_t stream) {
    const float* q   = (const float*)d_in[0];
    const float* k   = (const float*)d_in[1];
    const float* v   = (const float*)d_in[2];
    const int*   idx = (const int*)d_in[3];
    float* out = (float*)d_out;

    float* ws = (float*)d_ws;
    float* M      = ws;                         // B*H*L = 65536 (reused as meanv partials)
    int*   topidx = (int*)(ws + 65536);         // 1280 ints
    float* meanv  = ws + 65536 + 1280;          // 2048
    float* pm     = meanv + 2048;               // 10240
    float* pl     = pm + 10240;                 // 10240
    float* pctx   = pl + 10240;                 // 655360

    k_compute_M<<<B * L / 4, 256, 0, stream>>>(q, k, idx, M);
    k_topk<<<B * H, 256, 0, stream>>>(M, topidx);
    k_meanv_part<<<B * 32, 512, 0, stream>>>(v, M);
    k_meanv_final<<<B, 512, 0, stream>>>(M, meanv);
    k_attn_part<<<B * H * NCH, 256, 0, stream>>>(q, k, v, topidx, pctx, pm, pl);
    k_fill<<<(B * L * H * D / 4) / 256, 256, 0, stream>>>(meanv, (float4*)out);
    k_combine<<<B * H, 256, 0, stream>>>(topidx, pctx, pm, pl, out);
}

// Round 6
// 210.225 us; speedup vs baseline: 2.2179x; 1.0252x over previous
//
#include <hip/hip_runtime.h>
#include <math.h>

constexpr int B = 4, L = 2048, S = 2048, H = 8, D = 64;
constexpr int U  = 40;
constexpr int NT = 40;
constexpr int NCH = 8;
constexpr int CS = S / NCH;          // 256
constexpr float SCALE = 0.125f;

// ---------------------------------------------------------------- K1: M scores
__global__ void k_compute_M(const float* __restrict__ q, const float* __restrict__ k,
                            const int* __restrict__ idx, float* __restrict__ M) {
    int tid = threadIdx.x;
    int wid = tid >> 6, lane = tid & 63;
    int b = blockIdx.x & 3;
    int l = (blockIdx.x >> 2) * 4 + wid;
    int h = lane >> 3, dg = lane & 7;

    const float4* qr = (const float4*)(q + ((size_t)(b * L + l) * H + h) * D + dg * 8);
    float4 q0 = qr[0], q1 = qr[1];

    const int* irow = idx + l * U;
    const float* kb = k + (size_t)b * S * H * D + (size_t)h * D + dg * 8;
    float vmax = -INFINITY, vsum = 0.f;
#pragma unroll 4
    for (int u = 0; u < U; u++) {
        int s = irow[u];
        const float4* kr = (const float4*)(kb + (size_t)s * H * D);
        float4 k0 = kr[0], k1 = kr[1];
        float acc = q0.x * k0.x + q0.y * k0.y + q0.z * k0.z + q0.w * k0.w
                  + q1.x * k1.x + q1.y * k1.y + q1.z * k1.z + q1.w * k1.w;
        acc += __shfl_xor(acc, 1);
        acc += __shfl_xor(acc, 2);
        acc += __shfl_xor(acc, 4);
        vmax = fmaxf(vmax, acc);
        vsum += acc;
    }
    if (dg == 0) M[(size_t)(b * H + h) * L + l] = vmax - vsum / (float)S;
}

// ---------------------------------------------------------------- K2: top-40 via radix select
__device__ inline unsigned int fkey(float f) {
    unsigned int u = __float_as_uint(f);
    return (u & 0x80000000u) ? ~u : (u | 0x80000000u);
}

__global__ void k_topk(const float* __restrict__ M, int* __restrict__ topidx) {
    int bh = blockIdx.x;
    const float* m = M + (size_t)bh * L;
    int tid = threadIdx.x;

    __shared__ int hist[256];
    __shared__ unsigned int prefix_s;
    __shared__ int c_above_s, nsel_s, ntie_s, r_s;
    __shared__ int tie_i[L];

    unsigned int o[8];
    const float4* mr = (const float4*)(m + tid * 8);
    float4 a0 = mr[0], a1 = mr[1];
    o[0] = fkey(a0.x); o[1] = fkey(a0.y); o[2] = fkey(a0.z); o[3] = fkey(a0.w);
    o[4] = fkey(a1.x); o[5] = fkey(a1.y); o[6] = fkey(a1.z); o[7] = fkey(a1.w);

    if (tid == 0) { prefix_s = 0u; c_above_s = 0; nsel_s = 0; ntie_s = 0; }

    for (int sh = 24; sh >= 0; sh -= 8) {
        hist[tid] = 0;
        __syncthreads();
        unsigned int pfx = prefix_s;
#pragma unroll
        for (int j = 0; j < 8; j++) {
            bool match = (sh == 24) || ((o[j] >> (sh + 8)) == (pfx >> (sh + 8)));
            if (match) atomicAdd(&hist[(o[j] >> sh) & 0xFF], 1);
        }
        __syncthreads();
        if (tid == 0) {
            int acc = c_above_s, bstar = 0;
            for (int j2 = 255; j2 >= 0; j2--) {
                int c = hist[j2];
                if (acc + c >= NT) { bstar = j2; break; }
                acc += c;
            }
            c_above_s = acc;
            prefix_s = prefix_s | ((unsigned int)bstar << sh);
        }
        __syncthreads();
    }

    unsigned int T = prefix_s;

#pragma unroll
    for (int j = 0; j < 8; j++) {
        if (o[j] > T) {
            int slot = atomicAdd(&nsel_s, 1);
            topidx[bh * NT + slot] = tid * 8 + j;
        } else if (o[j] == T) {
            int p = atomicAdd(&ntie_s, 1);
            tie_i[p] = tid * 8 + j;
        }
    }
    __syncthreads();
    if (tid == 0) r_s = NT - nsel_s;
    __syncthreads();
    int r = r_s, ntie = ntie_s;

#pragma unroll
    for (int j = 0; j < 8; j++) {
        if (o[j] == T) {
            int myidx = tid * 8 + j;
            int rank = 0;
            for (int p = 0; p < ntie; p++) rank += (tie_i[p] < myidx) ? 1 : 0;
            if (rank < r) {
                int slot = atomicAdd(&nsel_s, 1);
                topidx[bh * NT + slot] = myidx;
            }
        }
    }
}

// ---------------------------------------------------------------- K3: v mean (2-phase)
__global__ void k_meanv_part(const float* __restrict__ v, float* __restrict__ part) {
    int blk = blockIdx.x;
    int b = blk >> 5, c = blk & 31;
    int col = threadIdx.x;
    const float* p = v + ((size_t)(b * S + c * 64)) * 512 + col;
    float acc = 0.f;
#pragma unroll
    for (int s = 0; s < 64; s++) acc += p[(size_t)s * 512];
    part[(size_t)blk * 512 + col] = acc;
}

__global__ void k_meanv_final(const float* __restrict__ part, float* __restrict__ meanv) {
    int b = blockIdx.x; int col = threadIdx.x;
    float acc = 0.f;
#pragma unroll
    for (int c = 0; c < 32; c++) acc += part[(size_t)(b * 32 + c) * 512 + col];
    meanv[b * 512 + col] = acc * (1.f / (float)S);
}

// ---------------------------------------------------------------- K4: attention partials
// Row stats are wave-parallel: wave w owns rows w*10..w*10+9; per row, lanes
// read 4 strided columns (bank = (4n+lane)&31, 2-way = free) and butterfly-
// reduce. No serial 256-element scans, no 40-thread bank-conflicted walks.
__global__ void k_attn_part(const float* __restrict__ q, const float* __restrict__ k,
                            const float* __restrict__ v, const int* __restrict__ topidx,
                            float* __restrict__ pctx, float* __restrict__ pm,
                            float* __restrict__ pl) {
    int blk = blockIdx.x;
    int bh = blk / NCH, c = blk % NCH;
    int b = bh / H, h = bh % H;
    int s0 = c * CS;
    int tid = threadIdx.x;
    int lane = tid & 63, g = tid >> 6;

    __shared__ float q_s[NT][D];
    __shared__ float p_s[NT][CS + 4];    // stride 260 floats
    __shared__ float m_c[NT];

    for (int i = tid; i < NT * D; i += 256) {
        int n = i / D, d = i % D;
        int lsel = topidx[bh * NT + n];
        q_s[n][d] = q[((size_t)(b * L + lsel) * H + h) * D + d];
    }
    __syncthreads();

    int s = s0 + tid;
    const float4* kr = (const float4*)(k + ((size_t)(b * S + s) * H + h) * D);
    float4 kv[16];
#pragma unroll
    for (int i = 0; i < 16; i++) kv[i] = kr[i];

    float sc[NT];
#pragma unroll
    for (int n = 0; n < NT; n++) {
        const float4* qr = (const float4*)q_s[n];
        float acc = 0.f;
#pragma unroll
        for (int i = 0; i < 16; i++) {
            float4 qv = qr[i];
            acc += qv.x * kv[i].x + qv.y * kv[i].y + qv.z * kv[i].z + qv.w * kv[i].w;
        }
        sc[n] = acc * SCALE;
        p_s[n][tid] = sc[n];
    }
    __syncthreads();

    // wave-parallel row max: wave g, rows g*10..g*10+9
#pragma unroll
    for (int j = 0; j < 10; j++) {
        int n = g * 10 + j;
        float a0 = p_s[n][lane], a1 = p_s[n][lane + 64];
        float a2 = p_s[n][lane + 128], a3 = p_s[n][lane + 192];
        float mx = fmaxf(fmaxf(a0, a1), fmaxf(a2, a3));
#pragma unroll
        for (int off = 1; off < 64; off <<= 1)
            mx = fmaxf(mx, __shfl_xor(mx, off));
        if (lane == 0) m_c[n] = mx;
    }
    __syncthreads();

    // exp in place (scores still in regs)
#pragma unroll
    for (int n = 0; n < NT; n++) p_s[n][tid] = __expf(sc[n] - m_c[n]);
    __syncthreads();

    // wave-parallel row sum + emit pm/pl
#pragma unroll
    for (int j = 0; j < 10; j++) {
        int n = g * 10 + j;
        float sum = p_s[n][lane] + p_s[n][lane + 64]
                  + p_s[n][lane + 128] + p_s[n][lane + 192];
#pragma unroll
        for (int off = 1; off < 64; off <<= 1)
            sum += __shfl_xor(sum, off);
        if (lane == 0) {
            pm[(bh * NCH + c) * NT + n] = m_c[n];
            pl[(bh * NCH + c) * NT + n] = sum;
        }
    }

    // partial ctx: wave g rows g*10..g*10+9, lane = d
    int d = lane;
    float acc[10];
#pragma unroll
    for (int j = 0; j < 10; j++) acc[j] = 0.f;
    const float* vb = v + ((size_t)(b * S + s0) * H + h) * D + d;
    for (int t4 = 0; t4 < CS; t4 += 4) {
        float vd0 = vb[(size_t)(t4 + 0) * H * D];
        float vd1 = vb[(size_t)(t4 + 1) * H * D];
        float vd2 = vb[(size_t)(t4 + 2) * H * D];
        float vd3 = vb[(size_t)(t4 + 3) * H * D];
#pragma unroll
        for (int j = 0; j < 10; j++) {
            float4 p4 = *(const float4*)&p_s[g * 10 + j][t4];
            acc[j] += p4.x * vd0 + p4.y * vd1 + p4.z * vd2 + p4.w * vd3;
        }
    }
    for (int j = 0; j < 10; j++)
        pctx[((size_t)(bh * NCH + c) * NT + g * 10 + j) * D + d] = acc[j];
}

// ---------------------------------------------------------------- K5: fill with mean
__global__ void k_fill(const float* __restrict__ meanv, float4* __restrict__ out) {
    int i = blockIdx.x * blockDim.x + threadIdx.x;
    int b = i >> 18;
    int col4 = i & 127;
    out[i] = ((const float4*)meanv)[(b << 7) | col4];
}

// ---------------------------------------------------------------- K6: combine + scatter
__global__ void k_combine(const int* __restrict__ topidx, const float* __restrict__ pctx,
                          const float* __restrict__ pm, const float* __restrict__ pl,
                          float* __restrict__ out) {
    int bh = blockIdx.x; int b = bh / H, h = bh % H;
    int tid = threadIdx.x;
    for (int i = tid; i < NT * D; i += 256) {
        int n = i / D, d = i % D;
        float mg = -INFINITY;
#pragma unroll
        for (int c = 0; c < NCH; c++) mg = fmaxf(mg, pm[(bh * NCH + c) * NT + n]);
        float lsum = 0.f, ctx = 0.f;
#pragma unroll
        for (int c = 0; c < NCH; c++) {
            float w = __expf(pm[(bh * NCH + c) * NT + n] - mg);
            lsum += pl[(bh * NCH + c) * NT + n] * w;
            ctx  += pctx[((size_t)(bh * NCH + c) * NT + n) * D + d] * w;
        }
        int lsel = topidx[bh * NT + n];
        out[((size_t)(b * L + lsel) * H + h) * D + d] = ctx / lsum;
    }
}

// ---------------------------------------------------------------- launch
extern "C" void kernel_launch(void* const* d_in, const int* in_sizes, int n_in,
                              void* d_out, int out_size, void* d_ws, size_t ws_size,
                              hipStream_t stream) {
    const float* q   = (const float*)d_in[0];
    const float* k   = (const float*)d_in[1];
    const float* v   = (const float*)d_in[2];
    const int*   idx = (const int*)d_in[3];
    float* out = (float*)d_out;

    float* ws = (float*)d_ws;
    float* M      = ws;                         // B*H*L = 65536 (reused as meanv partials)
    int*   topidx = (int*)(ws + 65536);         // 1280 ints
    float* meanv  = ws + 65536 + 1280;          // 2048
    float* pm     = meanv + 2048;               // 10240
    float* pl     = pm + 10240;                 // 10240
    float* pctx   = pl + 10240;                 // 655360

    k_compute_M<<<B * L / 4, 256, 0, stream>>>(q, k, idx, M);
    k_topk<<<B * H, 256, 0, stream>>>(M, topidx);
    k_meanv_part<<<B * 32, 512, 0, stream>>>(v, M);
    k_meanv_final<<<B, 512, 0, stream>>>(M, meanv);
    k_attn_part<<<B * H * NCH, 256, 0, stream>>>(q, k, v, topidx, pctx, pm, pl);
    k_fill<<<(B * L * H * D / 4) / 256, 256, 0, stream>>>(meanv, (float4*)out);
    k_combine<<<B * H, 256, 0, stream>>>(topidx, pctx, pm, pl, out);
}

// Round 7
// 168.330 us; speedup vs baseline: 2.7699x; 1.2489x over previous
//
#include <hip/hip_runtime.h>
#include <math.h>

constexpr int B = 4, L = 2048, S = 2048, H = 8, D = 64;
constexpr int U  = 40;
constexpr int NT = 40;
constexpr int NCH = 8;
constexpr int CS = S / NCH;          // 256
constexpr float SCALE = 0.125f;

// ---------------------------------------------------------------- K1: M scores
__global__ void k_compute_M(const float* __restrict__ q, const float* __restrict__ k,
                            const int* __restrict__ idx, float* __restrict__ M) {
    int tid = threadIdx.x;
    int wid = tid >> 6, lane = tid & 63;
    int b = blockIdx.x & 3;
    int l = (blockIdx.x >> 2) * 4 + wid;
    int h = lane >> 3, dg = lane & 7;

    const float4* qr = (const float4*)(q + ((size_t)(b * L + l) * H + h) * D + dg * 8);
    float4 q0 = qr[0], q1 = qr[1];

    const int* irow = idx + l * U;
    const float* kb = k + (size_t)b * S * H * D + (size_t)h * D + dg * 8;
    float vmax = -INFINITY, vsum = 0.f;
#pragma unroll 4
    for (int u = 0; u < U; u++) {
        int s = irow[u];
        const float4* kr = (const float4*)(kb + (size_t)s * H * D);
        float4 k0 = kr[0], k1 = kr[1];
        float acc = q0.x * k0.x + q0.y * k0.y + q0.z * k0.z + q0.w * k0.w
                  + q1.x * k1.x + q1.y * k1.y + q1.z * k1.z + q1.w * k1.w;
        acc += __shfl_xor(acc, 1);
        acc += __shfl_xor(acc, 2);
        acc += __shfl_xor(acc, 4);
        vmax = fmaxf(vmax, acc);
        vsum += acc;
    }
    if (dg == 0) M[(size_t)(b * H + h) * L + l] = vmax - vsum / (float)S;
}

// ---------------------------------------------------------------- K2: top-40 radix select
// Boundary-bin search is wave-parallel: lane holds 4 bins, Kogge-Stone suffix
// scan over lanes, per-lane boundary test. No serial 256-bin walks.
__device__ inline unsigned int fkey(float f) {
    unsigned int u = __float_as_uint(f);
    return (u & 0x80000000u) ? ~u : (u | 0x80000000u);
}

__global__ void k_topk(const float* __restrict__ M, int* __restrict__ topidx) {
    int bh = blockIdx.x;
    const float* m = M + (size_t)bh * L;
    int tid = threadIdx.x;

    __shared__ int hist[256];
    __shared__ unsigned int prefix_s;
    __shared__ int c_above_s, nsel_s, ntie_s, r_s;
    __shared__ int tie_i[L];

    unsigned int o[8];
    const float4* mr = (const float4*)(m + tid * 8);
    float4 a0 = mr[0], a1 = mr[1];
    o[0] = fkey(a0.x); o[1] = fkey(a0.y); o[2] = fkey(a0.z); o[3] = fkey(a0.w);
    o[4] = fkey(a1.x); o[5] = fkey(a1.y); o[6] = fkey(a1.z); o[7] = fkey(a1.w);

    if (tid == 0) { prefix_s = 0u; c_above_s = 0; nsel_s = 0; ntie_s = 0; }

    for (int sh = 24; sh >= 0; sh -= 8) {
        hist[tid] = 0;
        __syncthreads();
        unsigned int pfx = prefix_s;
#pragma unroll
        for (int j = 0; j < 8; j++) {
            bool match = (sh == 24) || ((o[j] >> (sh + 8)) == (pfx >> (sh + 8)));
            if (match) atomicAdd(&hist[(o[j] >> sh) & 0xFF], 1);
        }
        __syncthreads();
        if (tid < 64) {
            int4 hv = *(const int4*)&hist[tid * 4];
            int lsum = hv.x + hv.y + hv.z + hv.w;
            int s = lsum;
#pragma unroll
            for (int off = 1; off < 64; off <<= 1) {
                int t = __shfl_down(s, off);
                if (tid + off < 64) s += t;
            }
            int tail = s - lsum;              // count in bins >= 4*(tid+1)
            int acc = c_above_s;
            int need = NT - acc;
            int t3 = tail + hv.w;
            int t2 = t3 + hv.z;
            int t1 = t2 + hv.y;
            int t0 = t1 + hv.x;
            // boundary bin j*: suffix(j) >= need && suffix(j+1) < need
            if (t0 >= need && t1 < need) { prefix_s |= (unsigned)(4 * tid + 0) << sh; c_above_s = acc + t1; }
            else if (t1 >= need && t2 < need) { prefix_s |= (unsigned)(4 * tid + 1) << sh; c_above_s = acc + t2; }
            else if (t2 >= need && t3 < need) { prefix_s |= (unsigned)(4 * tid + 2) << sh; c_above_s = acc + t3; }
            else if (t3 >= need && tail < need) { prefix_s |= (unsigned)(4 * tid + 3) << sh; c_above_s = acc + tail; }
        }
        __syncthreads();
    }

    unsigned int T = prefix_s;

#pragma unroll
    for (int j = 0; j < 8; j++) {
        if (o[j] > T) {
            int slot = atomicAdd(&nsel_s, 1);
            topidx[bh * NT + slot] = tid * 8 + j;
        } else if (o[j] == T) {
            int p = atomicAdd(&ntie_s, 1);
            tie_i[p] = tid * 8 + j;
        }
    }
    __syncthreads();
    if (tid == 0) r_s = NT - nsel_s;
    __syncthreads();
    int r = r_s, ntie = ntie_s;

#pragma unroll
    for (int j = 0; j < 8; j++) {
        if (o[j] == T) {
            int myidx = tid * 8 + j;
            int rank = 0;
            for (int p = 0; p < ntie; p++) rank += (tie_i[p] < myidx) ? 1 : 0;
            if (rank < r) {
                int slot = atomicAdd(&nsel_s, 1);
                topidx[bh * NT + slot] = myidx;
            }
        }
    }
}

// ---------------------------------------------------------------- K3: v mean (2-phase)
__global__ void k_meanv_part(const float* __restrict__ v, float* __restrict__ part) {
    int blk = blockIdx.x;
    int b = blk >> 5, c = blk & 31;
    int col = threadIdx.x;
    const float* p = v + ((size_t)(b * S + c * 64)) * 512 + col;
    float acc = 0.f;
#pragma unroll
    for (int s = 0; s < 64; s++) acc += p[(size_t)s * 512];
    part[(size_t)blk * 512 + col] = acc;
}

__global__ void k_meanv_final(const float* __restrict__ part, float* __restrict__ meanv) {
    int b = blockIdx.x; int col = threadIdx.x;
    float acc = 0.f;
#pragma unroll
    for (int c = 0; c < 32; c++) acc += part[(size_t)(b * 32 + c) * 512 + col];
    meanv[b * 512 + col] = acc * (1.f / (float)S);
}

// ---------------------------------------------------------------- K4: attention partials
// 512 threads = 8 waves. Scores: wave = (row-group of 10) x (col-half of 128);
// lane owns 2 adjacent columns, d-chunked by 16 -> each q b128 read feeds 8
// FMAs; scores live in registers through exp (no LDS reload). Stats/PV: wave
// owns 5 rows.
__global__ __launch_bounds__(512) void k_attn_part(
        const float* __restrict__ q, const float* __restrict__ k,
        const float* __restrict__ v, const int* __restrict__ topidx,
        float* __restrict__ pctx, float* __restrict__ pm, float* __restrict__ pl) {
    int blk = blockIdx.x;
    int bh = blk / NCH, c = blk % NCH;
    int b = bh / H, h = bh % H;
    int s0 = c * CS;
    int tid = threadIdx.x;
    int lane = tid & 63, g = tid >> 6;   // 8 waves

    __shared__ float q_s[NT][D];
    __shared__ float p_s[NT][CS + 4];    // row stride 260 floats (1040 B, 16B-aligned)
    __shared__ float m_c[NT];

    for (int i = tid; i < NT * D; i += 512) {
        int n = i >> 6, d = i & 63;
        int lsel = topidx[bh * NT + n];
        q_s[n][d] = q[((size_t)(b * L + lsel) * H + h) * D + d];
    }
    __syncthreads();

    // ---- scores
    int r0 = (g & 3) * 10;
    int lc = ((g >> 2) << 7) + (lane << 1);          // local col, even
    const float* kp0 = k + ((size_t)(b * S + s0 + lc) * H + h) * D;
    const float* kp1 = kp0 + H * D;

    float sc0[10], sc1[10];
#pragma unroll
    for (int j = 0; j < 10; j++) { sc0[j] = 0.f; sc1[j] = 0.f; }

#pragma unroll
    for (int dc = 0; dc < 64; dc += 16) {
        float4 ka0 = *(const float4*)(kp0 + dc);
        float4 ka1 = *(const float4*)(kp0 + dc + 4);
        float4 ka2 = *(const float4*)(kp0 + dc + 8);
        float4 ka3 = *(const float4*)(kp0 + dc + 12);
        float4 kb0 = *(const float4*)(kp1 + dc);
        float4 kb1 = *(const float4*)(kp1 + dc + 4);
        float4 kb2 = *(const float4*)(kp1 + dc + 8);
        float4 kb3 = *(const float4*)(kp1 + dc + 12);
#pragma unroll
        for (int j = 0; j < 10; j++) {
            const float4* qr = (const float4*)&q_s[r0 + j][dc];
            float4 q0 = qr[0], q1 = qr[1], q2 = qr[2], q3 = qr[3];
            sc0[j] += q0.x * ka0.x + q0.y * ka0.y + q0.z * ka0.z + q0.w * ka0.w
                    + q1.x * ka1.x + q1.y * ka1.y + q1.z * ka1.z + q1.w * ka1.w
                    + q2.x * ka2.x + q2.y * ka2.y + q2.z * ka2.z + q2.w * ka2.w
                    + q3.x * ka3.x + q3.y * ka3.y + q3.z * ka3.z + q3.w * ka3.w;
            sc1[j] += q0.x * kb0.x + q0.y * kb0.y + q0.z * kb0.z + q0.w * kb0.w
                    + q1.x * kb1.x + q1.y * kb1.y + q1.z * kb1.z + q1.w * kb1.w
                    + q2.x * kb2.x + q2.y * kb2.y + q2.z * kb2.z + q2.w * kb2.w
                    + q3.x * kb3.x + q3.y * kb3.y + q3.z * kb3.z + q3.w * kb3.w;
        }
    }
#pragma unroll
    for (int j = 0; j < 10; j++) {
        sc0[j] *= SCALE; sc1[j] *= SCALE;
        *(float2*)&p_s[r0 + j][lc] = make_float2(sc0[j], sc1[j]);
    }
    __syncthreads();

    // ---- row max (wave g: rows g*5..g*5+5); bank = (4n+lane)&31 -> 2-way, free
#pragma unroll
    for (int j = 0; j < 5; j++) {
        int n = g * 5 + j;
        float mx = fmaxf(fmaxf(p_s[n][lane], p_s[n][lane + 64]),
                         fmaxf(p_s[n][lane + 128], p_s[n][lane + 192]));
#pragma unroll
        for (int off = 1; off < 64; off <<= 1)
            mx = fmaxf(mx, __shfl_xor(mx, off));
        if (lane == 0) m_c[n] = mx;
    }
    __syncthreads();

    // ---- exp from registers
#pragma unroll
    for (int j = 0; j < 10; j++) {
        float mm = m_c[r0 + j];
        *(float2*)&p_s[r0 + j][lc] =
            make_float2(__expf(sc0[j] - mm), __expf(sc1[j] - mm));
    }
    __syncthreads();

    // ---- row sum + emit pm/pl
#pragma unroll
    for (int j = 0; j < 5; j++) {
        int n = g * 5 + j;
        float sum = p_s[n][lane] + p_s[n][lane + 64]
                  + p_s[n][lane + 128] + p_s[n][lane + 192];
#pragma unroll
        for (int off = 1; off < 64; off <<= 1) sum += __shfl_xor(sum, off);
        if (lane == 0) {
            pm[(bh * NCH + c) * NT + n] = m_c[n];
            pl[(bh * NCH + c) * NT + n] = sum;
        }
    }

    // ---- PV: wave g rows g*5..g*5+5, lane = d
    float acc[5];
#pragma unroll
    for (int j = 0; j < 5; j++) acc[j] = 0.f;
    const float* vb = v + ((size_t)(b * S + s0) * H + h) * D + lane;
    int rp = g * 5;
    for (int t4 = 0; t4 < CS; t4 += 4) {
        float vd0 = vb[(size_t)(t4 + 0) * H * D];
        float vd1 = vb[(size_t)(t4 + 1) * H * D];
        float vd2 = vb[(size_t)(t4 + 2) * H * D];
        float vd3 = vb[(size_t)(t4 + 3) * H * D];
#pragma unroll
        for (int j = 0; j < 5; j++) {
            float4 p4 = *(const float4*)&p_s[rp + j][t4];
            acc[j] += p4.x * vd0 + p4.y * vd1 + p4.z * vd2 + p4.w * vd3;
        }
    }
#pragma unroll
    for (int j = 0; j < 5; j++)
        pctx[((size_t)(bh * NCH + c) * NT + rp + j) * D + lane] = acc[j];
}

// ---------------------------------------------------------------- K5: fill with mean
__global__ void k_fill(const float* __restrict__ meanv, float4* __restrict__ out) {
    int i = blockIdx.x * blockDim.x + threadIdx.x;
    int b = i >> 18;
    int col4 = i & 127;
    out[i] = ((const float4*)meanv)[(b << 7) | col4];
}

// ---------------------------------------------------------------- K6: combine + scatter
__global__ void k_combine(const int* __restrict__ topidx, const float* __restrict__ pctx,
                          const float* __restrict__ pm, const float* __restrict__ pl,
                          float* __restrict__ out) {
    int bh = blockIdx.x; int b = bh / H, h = bh % H;
    int tid = threadIdx.x;
    for (int i = tid; i < NT * D; i += 256) {
        int n = i / D, d = i % D;
        float mg = -INFINITY;
#pragma unroll
        for (int c = 0; c < NCH; c++) mg = fmaxf(mg, pm[(bh * NCH + c) * NT + n]);
        float lsum = 0.f, ctx = 0.f;
#pragma unroll
        for (int c = 0; c < NCH; c++) {
            float w = __expf(pm[(bh * NCH + c) * NT + n] - mg);
            lsum += pl[(bh * NCH + c) * NT + n] * w;
            ctx  += pctx[((size_t)(bh * NCH + c) * NT + n) * D + d] * w;
        }
        int lsel = topidx[bh * NT + n];
        out[((size_t)(b * L + lsel) * H + h) * D + d] = ctx / lsum;
    }
}

// ---------------------------------------------------------------- launch
extern "C" void kernel_launch(void* const* d_in, const int* in_sizes, int n_in,
                              void* d_out, int out_size, void* d_ws, size_t ws_size,
                              hipStream_t stream) {
    const float* q   = (const float*)d_in[0];
    const float* k   = (const float*)d_in[1];
    const float* v   = (const float*)d_in[2];
    const int*   idx = (const int*)d_in[3];
    float* out = (float*)d_out;

    float* ws = (float*)d_ws;
    float* M      = ws;                         // B*H*L = 65536 (reused as meanv partials)
    int*   topidx = (int*)(ws + 65536);         // 1280 ints
    float* meanv  = ws + 65536 + 1280;          // 2048
    float* pm     = meanv + 2048;               // 10240
    float* pl     = pm + 10240;                 // 10240
    float* pctx   = pl + 10240;                 // 655360

    k_compute_M<<<B * L / 4, 256, 0, stream>>>(q, k, idx, M);
    k_topk<<<B * H, 256, 0, stream>>>(M, topidx);
    k_meanv_part<<<B * 32, 512, 0, stream>>>(v, M);
    k_meanv_final<<<B, 512, 0, stream>>>(M, meanv);
    k_attn_part<<<B * H * NCH, 512, 0, stream>>>(q, k, v, topidx, pctx, pm, pl);
    k_fill<<<(B * L * H * D / 4) / 256, 256, 0, stream>>>(meanv, (float4*)out);
    k_combine<<<B * H, 256, 0, stream>>>(topidx, pctx, pm, pl, out);
}